// Round 1
// baseline (1039.730 us; speedup 1.0000x reference)
//
#include <hip/hip_runtime.h>
#include <hip/hip_bf16.h>
#include <math.h>

// Problem constants: B=2, S=2048, D=1024, HQ=16, HKV=8, DK=DV=64
// ws layout (float offsets):
#define WS_Q    0u          // [2][16][2048][64] = 4194304 f32 (RoPE'd Q)
#define WS_K    4194304u    // [2][8][2048][64]  = 2097152 f32 (RoPE'd K)
#define WS_V    6291456u    // [2][8][2048][64]  = 2097152 f32
#define WS_AO   8388608u    // [4096][1024]      = 4194304 f32 (attn out, pre out-proj)
#define WS_MASK 12582912u   // 4096 u32 canonical mask

// ---------------- mask canonicalization (detect u8 / i32 / f32 storage) ---------
__global__ void mask_canon_kernel(const void* __restrict__ mraw,
                                  unsigned* __restrict__ mout) {
    __shared__ int bad01, badf;
    const int tid = threadIdx.x;            // 1024 threads, 1 block
    if (tid == 0) { bad01 = 0; badf = 0; }
    __syncthreads();
    const unsigned* w = (const unsigned*)mraw;
    const unsigned v = w[tid];              // first 4 KiB valid for all 3 formats
    if (v > 1u) atomicAdd(&bad01, 1);
    if (v != 0u && v != 0x3F800000u) atomicAdd(&badf, 1);
    __syncthreads();
    const int fmt = (bad01 == 0) ? 0 : ((badf == 0) ? 1 : 2); // 0=i32, 1=f32, 2=u8
    for (int i = tid; i < 4096; i += 1024) {
        unsigned r;
        if (fmt == 0)      r = w[i];
        else if (fmt == 1) r = (w[i] != 0u) ? 1u : 0u;
        else               r = (((const unsigned char*)mraw)[i] != 0) ? 1u : 0u;
        mout[i] = r;
    }
}

// ---------------- fused QKV projection + bias + RoPE --------------------------
// x(4096x1024) @ [Wq|Wk|Wv](1024x{1024,512,512}); 128x128 tiles, 256 thr, 8x8 micro
__launch_bounds__(256)
__global__ void qkv_rope_kernel(const float* __restrict__ x,
                                const float* __restrict__ Wq, const float* __restrict__ bq,
                                const float* __restrict__ Wk, const float* __restrict__ bk,
                                const float* __restrict__ Wv, const float* __restrict__ bv,
                                const float* __restrict__ fc, const float* __restrict__ fs,
                                float* __restrict__ ws) {
    __shared__ float Asm[16][132];   // A staged transposed [k][m], padded
    __shared__ float Bsm[16][128];   // B staged [k][n]
    const int tid = threadIdx.x;
    const int tx = tid & 15, ty = tid >> 4;
    const int m0 = blockIdx.y * 128;
    const int nb = blockIdx.x * 128;
    const float* Wp; const float* bp; int ldw, cb, region;
    if (nb < 1024)      { Wp = Wq; bp = bq; ldw = 1024; cb = nb;        region = 0; }
    else if (nb < 1536) { Wp = Wk; bp = bk; ldw = 512;  cb = nb - 1024; region = 1; }
    else                { Wp = Wv; bp = bv; ldw = 512;  cb = nb - 1536; region = 2; }

    float acc[8][8];
#pragma unroll
    for (int r = 0; r < 8; ++r)
#pragma unroll
        for (int c = 0; c < 8; ++c) acc[r][c] = 0.f;

    for (int k0 = 0; k0 < 1024; k0 += 16) {
#pragma unroll
        for (int j = 0; j < 2; ++j) {
            const int f = tid + 256 * j;
            const int m = f >> 2, k4 = (f & 3) << 2;
            const float4 av = *(const float4*)&x[(m0 + m) * 1024 + k0 + k4];
            Asm[k4 + 0][m] = av.x; Asm[k4 + 1][m] = av.y;
            Asm[k4 + 2][m] = av.z; Asm[k4 + 3][m] = av.w;
            const int kb = f >> 5, n4 = (f & 31) << 2;
            *(float4*)&Bsm[kb][n4] = *(const float4*)&Wp[(k0 + kb) * ldw + cb + n4];
        }
        __syncthreads();
#pragma unroll
        for (int kk = 0; kk < 16; ++kk) {
            const float4 a0 = *(const float4*)&Asm[kk][8 * ty];
            const float4 a1 = *(const float4*)&Asm[kk][8 * ty + 4];
            const float4 b0 = *(const float4*)&Bsm[kk][8 * tx];
            const float4 b1 = *(const float4*)&Bsm[kk][8 * tx + 4];
            const float a[8] = {a0.x,a0.y,a0.z,a0.w,a1.x,a1.y,a1.z,a1.w};
            const float bv2[8] = {b0.x,b0.y,b0.z,b0.w,b1.x,b1.y,b1.z,b1.w};
#pragma unroll
            for (int r = 0; r < 8; ++r)
#pragma unroll
                for (int c = 0; c < 8; ++c) acc[r][c] += a[r] * bv2[c];
        }
        __syncthreads();
    }
    // epilogue: bias + RoPE (Q/K) + scatter to head-major layouts
#pragma unroll
    for (int r = 0; r < 8; ++r) {
        const int tok = m0 + 8 * ty + r;
        const int bb = tok >> 11, sp = tok & 2047;
#pragma unroll
        for (int j = 0; j < 8; j += 2) {
            const int cr = cb + 8 * tx + j;      // col within region
            const float v1 = acc[r][j]     + bp[cr];
            const float v2 = acc[r][j + 1] + bp[cr + 1];
            const int h = cr >> 6;
            if (region == 2) {
                const int dv = cr & 63;
                *(float2*)&ws[WS_V + (((bb * 8 + h) * 2048 + sp) * 64 + dv)] =
                    make_float2(v1, v2);
            } else {
                const int dk = cr & 63;
                const float cz = fc[sp * 32 + (dk >> 1)];
                const float sz = fs[sp * 32 + (dk >> 1)];
                const float o1 = v1 * cz - v2 * sz;
                const float o2 = v1 * sz + v2 * cz;
                const unsigned base = (region == 0)
                    ? (WS_Q + (unsigned)(((bb * 16 + h) * 2048 + sp) * 64 + dk))
                    : (WS_K + (unsigned)(((bb * 8 + h) * 2048 + sp) * 64 + dk));
                *(float2*)&ws[base] = make_float2(o1, o2);
            }
        }
    }
}

// ---------------- flash attention fp32: Q-tile 64, K-tile 64 -------------------
// grid (32 qtiles, 16 heads, 2 batch), 256 thr (tx=16 x ty=16), micro 4q x 4k
__launch_bounds__(256)
__global__ void attn_kernel(float* __restrict__ ws, const unsigned* __restrict__ mask) {
    __shared__ float QtT[64][68];   // [d][q]
    __shared__ float KtT[64][68];   // [d][key]
    __shared__ float PtT[64][68];   // [key][q]
    const int tid = threadIdx.x;
    const int tx = tid & 15, ty = tid >> 4;
    const int q0 = blockIdx.x * 64;
    const int h  = blockIdx.y;
    const int b  = blockIdx.z;
    const float* Qb = ws + WS_Q + (b * 16 + h) * (2048 * 64);
    const float* Kb = ws + WS_K + (b * 8 + (h >> 1)) * (2048 * 64);
    const float* Vb = ws + WS_V + (b * 8 + (h >> 1)) * (2048 * 64);
    const unsigned* mrow = mask + b * 2048;

#pragma unroll
    for (int j = 0; j < 4; ++j) {
        const int f = tid + 256 * j;
        const int row = f >> 4, d4 = (f & 15) << 2;
        const float4 qv = *(const float4*)&Qb[(q0 + row) * 64 + d4];
        QtT[d4 + 0][row] = qv.x; QtT[d4 + 1][row] = qv.y;
        QtT[d4 + 2][row] = qv.z; QtT[d4 + 3][row] = qv.w;
    }

    float o[4][4];
    float m_r[4], l_r[4];
#pragma unroll
    for (int r = 0; r < 4; ++r) {
        m_r[r] = -INFINITY; l_r[r] = 0.f;
#pragma unroll
        for (int c = 0; c < 4; ++c) o[r][c] = 0.f;
    }

    for (int kt = 0; kt < 32; ++kt) {
        const int k0 = kt * 64;
#pragma unroll
        for (int j = 0; j < 4; ++j) {
            const int f = tid + 256 * j;
            const int row = f >> 4, d4 = (f & 15) << 2;
            const float4 kv = *(const float4*)&Kb[(k0 + row) * 64 + d4];
            KtT[d4 + 0][row] = kv.x; KtT[d4 + 1][row] = kv.y;
            KtT[d4 + 2][row] = kv.z; KtT[d4 + 3][row] = kv.w;
        }
        __syncthreads();   // B1: K staged; also protects PtT overwrite below

        float sc[4][4];
#pragma unroll
        for (int r = 0; r < 4; ++r)
#pragma unroll
            for (int c = 0; c < 4; ++c) sc[r][c] = 0.f;

#pragma unroll 8
        for (int d = 0; d < 64; ++d) {
            const float4 q4 = *(const float4*)&QtT[d][4 * ty];
            const float qa[4] = {q4.x, q4.y, q4.z, q4.w};
            const float kv[4] = {KtT[d][tx], KtT[d][tx + 16],
                                 KtT[d][tx + 32], KtT[d][tx + 48]};
#pragma unroll
            for (int r = 0; r < 4; ++r)
#pragma unroll
                for (int c = 0; c < 4; ++c) sc[r][c] += qa[r] * kv[c];
        }

        float ps[4][4];
#pragma unroll
        for (int r = 0; r < 4; ++r) {
            const int qg = q0 + 4 * ty + r;
            float mt = -INFINITY;
#pragma unroll
            for (int c = 0; c < 4; ++c) {
                const int kg = k0 + tx + 16 * c;
                float sv = sc[r][c] * 0.125f;
                const bool ok = (kg <= qg) || (mrow[kg] != 0u);
                sv = ok ? sv : -INFINITY;
                sc[r][c] = sv;
                mt = fmaxf(mt, sv);
            }
#pragma unroll
            for (int off = 1; off < 16; off <<= 1)
                mt = fmaxf(mt, __shfl_xor(mt, off, 16));
            const float mn = fmaxf(m_r[r], mt);
            float alpha, rs = 0.f;
            if (mn == -INFINITY) {          // fully-masked so far: keep state
                alpha = 1.f;
#pragma unroll
                for (int c = 0; c < 4; ++c) ps[r][c] = 0.f;
            } else {
                alpha = __expf(m_r[r] - mn);            // exp(-inf)=0 ok
#pragma unroll
                for (int c = 0; c < 4; ++c) {
                    const float p = __expf(sc[r][c] - mn);
                    ps[r][c] = p; rs += p;
                }
            }
#pragma unroll
            for (int off = 1; off < 16; off <<= 1)
                rs += __shfl_xor(rs, off, 16);
            m_r[r] = mn;
            l_r[r] = l_r[r] * alpha + rs;
#pragma unroll
            for (int c = 0; c < 4; ++c) o[r][c] *= alpha;
        }
#pragma unroll
        for (int c = 0; c < 4; ++c) {       // P -> LDS, [key][q], conflict-free f4
            const float4 pv = make_float4(ps[0][c], ps[1][c], ps[2][c], ps[3][c]);
            *(float4*)&PtT[tx + 16 * c][4 * ty] = pv;
        }
        __syncthreads();   // B2: P visible; all QK reads of KtT done

        const float* Vt = Vb + k0 * 64;
#pragma unroll 4
        for (int key = 0; key < 64; ++key) {
            const float4 p4 = *(const float4*)&PtT[key][4 * ty];
            const float4 v4 = *(const float4*)&Vt[key * 64 + 4 * tx];
            const float pa[4] = {p4.x, p4.y, p4.z, p4.w};
            const float va[4] = {v4.x, v4.y, v4.z, v4.w};
#pragma unroll
            for (int r = 0; r < 4; ++r)
#pragma unroll
                for (int c = 0; c < 4; ++c) o[r][c] += pa[r] * va[c];
        }
        // no barrier needed: next iter writes KtT (not PtT/QtT); B1 protects PtT
    }

#pragma unroll
    for (int r = 0; r < 4; ++r) {
        const int tok = b * 2048 + q0 + 4 * ty + r;
        const float inv = 1.f / l_r[r];
        const float4 st = make_float4(o[r][0]*inv, o[r][1]*inv, o[r][2]*inv, o[r][3]*inv);
        *(float4*)&ws[WS_AO + (unsigned)(tok * 1024 + h * 64 + 4 * tx)] = st;
    }
}

// ---------------- output projection: AO(4096x1024) @ Wo(1024x1024) + bo -------
__launch_bounds__(256)
__global__ void out_proj_kernel(const float* __restrict__ ao,
                                const float* __restrict__ Wo,
                                const float* __restrict__ bo,
                                float* __restrict__ out) {
    __shared__ float Asm[16][132];
    __shared__ float Bsm[16][64];
    const int tid = threadIdx.x;
    const int tx = tid & 15, ty = tid >> 4;
    const int m0 = blockIdx.y * 128;
    const int n0 = blockIdx.x * 64;
    float acc[8][4];
#pragma unroll
    for (int r = 0; r < 8; ++r)
#pragma unroll
        for (int c = 0; c < 4; ++c) acc[r][c] = 0.f;

    for (int k0 = 0; k0 < 1024; k0 += 16) {
#pragma unroll
        for (int j = 0; j < 2; ++j) {
            const int f = tid + 256 * j;
            const int m = f >> 2, k4 = (f & 3) << 2;
            const float4 av = *(const float4*)&ao[(m0 + m) * 1024 + k0 + k4];
            Asm[k4 + 0][m] = av.x; Asm[k4 + 1][m] = av.y;
            Asm[k4 + 2][m] = av.z; Asm[k4 + 3][m] = av.w;
        }
        {
            const int kb = tid >> 4, n4 = (tid & 15) << 2;
            *(float4*)&Bsm[kb][n4] = *(const float4*)&Wo[(k0 + kb) * 1024 + n0 + n4];
        }
        __syncthreads();
#pragma unroll
        for (int kk = 0; kk < 16; ++kk) {
            const float4 a0 = *(const float4*)&Asm[kk][8 * ty];
            const float4 a1 = *(const float4*)&Asm[kk][8 * ty + 4];
            const float4 b0 = *(const float4*)&Bsm[kk][4 * tx];
            const float a[8] = {a0.x,a0.y,a0.z,a0.w,a1.x,a1.y,a1.z,a1.w};
            const float bb[4] = {b0.x,b0.y,b0.z,b0.w};
#pragma unroll
            for (int r = 0; r < 8; ++r)
#pragma unroll
                for (int c = 0; c < 4; ++c) acc[r][c] += a[r] * bb[c];
        }
        __syncthreads();
    }
#pragma unroll
    for (int r = 0; r < 8; ++r) {
        const int row = m0 + 8 * ty + r;
        const float4 bv = *(const float4*)&bo[n0 + 4 * tx];
        const float4 st = make_float4(acc[r][0] + bv.x, acc[r][1] + bv.y,
                                      acc[r][2] + bv.z, acc[r][3] + bv.w);
        *(float4*)&out[row * 1024 + n0 + 4 * tx] = st;
    }
}

extern "C" void kernel_launch(void* const* d_in, const int* in_sizes, int n_in,
                              void* d_out, int out_size, void* d_ws, size_t ws_size,
                              hipStream_t stream) {
    const float* x  = (const float*)d_in[0];
    const float* Wq = (const float*)d_in[1];
    const float* bq = (const float*)d_in[2];
    const float* Wk = (const float*)d_in[3];
    const float* bk = (const float*)d_in[4];
    const float* Wv = (const float*)d_in[5];
    const float* bv = (const float*)d_in[6];
    const float* Wo = (const float*)d_in[7];
    const float* bo = (const float*)d_in[8];
    const float* fc = (const float*)d_in[9];
    const float* fs = (const float*)d_in[10];
    const void*  am = d_in[11];

    float* ws = (float*)d_ws;
    unsigned* maskw = (unsigned*)(ws + WS_MASK);
    float* out = (float*)d_out;

    hipLaunchKernelGGL(mask_canon_kernel, dim3(1), dim3(1024), 0, stream, am, maskw);
    hipLaunchKernelGGL(qkv_rope_kernel, dim3(16, 32), dim3(256), 0, stream,
                       x, Wq, bq, Wk, bk, Wv, bv, fc, fs, ws);
    hipLaunchKernelGGL(attn_kernel, dim3(32, 16, 2), dim3(256), 0, stream, ws, maskw);
    hipLaunchKernelGGL(out_proj_kernel, dim3(16, 32), dim3(256), 0, stream,
                       ws + WS_AO, Wo, bo, out);
}

// Round 2
// 470.459 us; speedup vs baseline: 2.2100x; 2.2100x over previous
//
#include <hip/hip_runtime.h>
#include <hip/hip_bf16.h>
#include <math.h>

// Problem constants: B=2, S=2048, D=1024, HQ=16, HKV=8, DK=DV=64
typedef __attribute__((ext_vector_type(8))) short bf16x8;   // 8 bf16 (4 VGPRs)
typedef __attribute__((ext_vector_type(4))) float f32x4;

// ws layout (byte offsets)
#define OFF_QB  0ull            // bf16 [2][16][2048][64]  8 MB   (pre-scaled by 0.125)
#define OFF_KB  (8ull<<20)      // bf16 [2][8][2048][64]   4 MB
#define OFF_VT  (12ull<<20)     // bf16 [2][8][64][2048]   4 MB   (V transposed: [d][key])
#define OFF_AO  (16ull<<20)     // f32  [4096][1024]      16 MB
#define OFF_MB  (32ull<<20)     // f32  [2][2048] mask bias (0 or -1e30)

__device__ inline unsigned pack_bf162(float a, float b) {
    __hip_bfloat162 t = __float22bfloat162_rn(make_float2(a, b));  // a -> low 16 bits
    return *(unsigned*)&t;
}

// ---------------- mask canonicalization -> float bias (0 / -1e30) -------------
__global__ void mask_canon_kernel(const void* __restrict__ mraw,
                                  float* __restrict__ mbias) {
    __shared__ int bad01, badf;
    const int tid = threadIdx.x;            // 1024 threads, 1 block
    if (tid == 0) { bad01 = 0; badf = 0; }
    __syncthreads();
    const unsigned* w = (const unsigned*)mraw;
    const unsigned v = w[tid];              // first 4 KiB valid for all 3 formats
    if (v > 1u) atomicAdd(&bad01, 1);
    if (v != 0u && v != 0x3F800000u) atomicAdd(&badf, 1);
    __syncthreads();
    const int fmt = (bad01 == 0) ? 0 : ((badf == 0) ? 1 : 2); // 0=i32, 1=f32, 2=u8
    for (int i = tid; i < 4096; i += 1024) {
        bool on;
        if (fmt == 0)      on = (w[i] != 0u);
        else if (fmt == 1) on = (w[i] != 0u);
        else               on = (((const unsigned char*)mraw)[i] != 0);
        mbias[i] = on ? 0.f : -1e30f;
    }
}

// ---------------- fused QKV projection + bias + RoPE -> bf16 Q,K,V^T ----------
__launch_bounds__(256)
__global__ void qkv_rope_kernel(const float* __restrict__ x,
                                const float* __restrict__ Wq, const float* __restrict__ bq,
                                const float* __restrict__ Wk, const float* __restrict__ bk,
                                const float* __restrict__ Wv, const float* __restrict__ bv,
                                const float* __restrict__ fc, const float* __restrict__ fs,
                                __hip_bfloat16* __restrict__ QB,
                                __hip_bfloat16* __restrict__ KB,
                                __hip_bfloat16* __restrict__ VT) {
    __shared__ float Asm[16][132];   // A staged transposed [k][m], padded
    __shared__ float Bsm[16][128];   // B staged [k][n]
    const int tid = threadIdx.x;
    const int tx = tid & 15, ty = tid >> 4;
    const int m0 = blockIdx.y * 128;
    const int nb = blockIdx.x * 128;
    const float* Wp; const float* bp; int ldw, cb, region;
    if (nb < 1024)      { Wp = Wq; bp = bq; ldw = 1024; cb = nb;        region = 0; }
    else if (nb < 1536) { Wp = Wk; bp = bk; ldw = 512;  cb = nb - 1024; region = 1; }
    else                { Wp = Wv; bp = bv; ldw = 512;  cb = nb - 1536; region = 2; }

    float acc[8][8];
#pragma unroll
    for (int r = 0; r < 8; ++r)
#pragma unroll
        for (int c = 0; c < 8; ++c) acc[r][c] = 0.f;

    for (int k0 = 0; k0 < 1024; k0 += 16) {
#pragma unroll
        for (int j = 0; j < 2; ++j) {
            const int f = tid + 256 * j;
            const int m = f >> 2, k4 = (f & 3) << 2;
            const float4 av = *(const float4*)&x[(m0 + m) * 1024 + k0 + k4];
            Asm[k4 + 0][m] = av.x; Asm[k4 + 1][m] = av.y;
            Asm[k4 + 2][m] = av.z; Asm[k4 + 3][m] = av.w;
            const int kb = f >> 5, n4 = (f & 31) << 2;
            *(float4*)&Bsm[kb][n4] = *(const float4*)&Wp[(k0 + kb) * ldw + cb + n4];
        }
        __syncthreads();
#pragma unroll
        for (int kk = 0; kk < 16; ++kk) {
            const float4 a0 = *(const float4*)&Asm[kk][8 * ty];
            const float4 a1 = *(const float4*)&Asm[kk][8 * ty + 4];
            const float4 b0 = *(const float4*)&Bsm[kk][8 * tx];
            const float4 b1 = *(const float4*)&Bsm[kk][8 * tx + 4];
            const float a[8] = {a0.x,a0.y,a0.z,a0.w,a1.x,a1.y,a1.z,a1.w};
            const float bv2[8] = {b0.x,b0.y,b0.z,b0.w,b1.x,b1.y,b1.z,b1.w};
#pragma unroll
            for (int r = 0; r < 8; ++r)
#pragma unroll
                for (int c = 0; c < 8; ++c) acc[r][c] += a[r] * bv2[c];
        }
        __syncthreads();
    }
    // epilogue: bias + RoPE (Q/K) + bf16 scatter (Q pre-scaled by 1/8; V transposed)
#pragma unroll
    for (int r = 0; r < 8; ++r) {
        const int tok = m0 + 8 * ty + r;
        const int bb = tok >> 11, sp = tok & 2047;
#pragma unroll
        for (int j = 0; j < 8; j += 2) {
            const int cr = cb + 8 * tx + j;      // col within region
            const float v1 = acc[r][j]     + bp[cr];
            const float v2 = acc[r][j + 1] + bp[cr + 1];
            const int h = cr >> 6;
            if (region == 2) {
                const int dv = cr & 63;
                VT[(size_t)((bb * 8 + h) * 64 + dv)     * 2048 + sp] = __float2bfloat16(v1);
                VT[(size_t)((bb * 8 + h) * 64 + dv + 1) * 2048 + sp] = __float2bfloat16(v2);
            } else {
                const int dk = cr & 63;
                const float cz = fc[sp * 32 + (dk >> 1)];
                const float sz = fs[sp * 32 + (dk >> 1)];
                float o1 = v1 * cz - v2 * sz;
                float o2 = v1 * sz + v2 * cz;
                if (region == 0) {
                    o1 *= 0.125f; o2 *= 0.125f;   // fold softmax scale into Q (exact)
                    *(__hip_bfloat162*)&QB[(size_t)((bb * 16 + h) * 2048 + sp) * 64 + dk] =
                        __float22bfloat162_rn(make_float2(o1, o2));
                } else {
                    *(__hip_bfloat162*)&KB[(size_t)((bb * 8 + h) * 2048 + sp) * 64 + dk] =
                        __float22bfloat162_rn(make_float2(o1, o2));
                }
            }
        }
    }
}

// ---------------- flash attention, bf16 MFMA, swapped operands ----------------
// grid (16 qtiles of 128, 16 heads, 2 batch), 256 thr = 4 waves.
// Per wave: 32 q-rows (2 rt x 16). S^T = mfma(K, Q^T): lane owns q = lane&15,
// keys 16*mt + 4*(lane>>4) + reg. O^T = mfma(V^T, P) with P redistributed via a
// per-wave XOR-swizzled LDS tile (no barriers in the k-loop).
__launch_bounds__(256)
__global__ void attn_kernel(const __hip_bfloat16* __restrict__ QB,
                            const __hip_bfloat16* __restrict__ KB,
                            const __hip_bfloat16* __restrict__ VT,
                            const float* __restrict__ maskb,
                            float* __restrict__ AO) {
    __shared__ float bias_sm[2048];
    __shared__ char  P_lds[4][4096];   // per wave: 2 rt x [16 q][64 key] bf16 (2 KB each)

    const int tid  = threadIdx.x;
    const int lane = tid & 63, wid = tid >> 6;
    const int c = lane & 15, g = lane >> 4;
    const int h = blockIdx.y, b = blockIdx.z;
    const int qb = blockIdx.x * 128 + wid * 32;

    {   // stage mask bias for this batch
        const float* mb = maskb + b * 2048;
        for (int i = tid; i < 512; i += 256)
            *(float4*)&bias_sm[4 * i] = *(const float4*)&mb[4 * i];
    }

    const __hip_bfloat16* Qh = QB + (size_t)(b * 16 + h)        * 2048 * 64;
    const __hip_bfloat16* Kh = KB + (size_t)(b * 8 + (h >> 1))  * 2048 * 64;
    const __hip_bfloat16* Vh = VT + (size_t)(b * 8 + (h >> 1))  * 64 * 2048;

    // Q frags (B-operand of S^T): col q = lane&15, k(d) = 8*g + j (+32*ks)
    bf16x8 bq[2][2];
#pragma unroll
    for (int rt = 0; rt < 2; ++rt)
#pragma unroll
        for (int ks = 0; ks < 2; ++ks)
            bq[rt][ks] = *(const bf16x8*)&Qh[(qb + 16 * rt + c) * 64 + 32 * ks + 8 * g];

    __syncthreads();

    f32x4 o[2][4];
#pragma unroll
    for (int rt = 0; rt < 2; ++rt)
#pragma unroll
        for (int mt = 0; mt < 4; ++mt) o[rt][mt] = f32x4{0.f, 0.f, 0.f, 0.f};
    float m_[2] = {-INFINITY, -INFINITY}, l_[2] = {0.f, 0.f};

    char* Pw = &P_lds[wid][0];
    const int swz = (c & 7) << 4;

    for (int kt = 0; kt < 32; ++kt) {
        const int k0 = kt * 64;
        // K frags (A-operand): row key = 16*mt + c, k(d) = 8*g + j (+32*ks)
        bf16x8 ak[4][2];
#pragma unroll
        for (int mt = 0; mt < 4; ++mt)
#pragma unroll
            for (int ks = 0; ks < 2; ++ks)
                ak[mt][ks] = *(const bf16x8*)&Kh[(k0 + 16 * mt + c) * 64 + 32 * ks + 8 * g];

        // S^T[key][q], fp32 acc; scores already include 1/8 scale (folded into Q)
        f32x4 st[2][4];
#pragma unroll
        for (int rt = 0; rt < 2; ++rt)
#pragma unroll
            for (int mt = 0; mt < 4; ++mt) {
                f32x4 z = f32x4{0.f, 0.f, 0.f, 0.f};
                z = __builtin_amdgcn_mfma_f32_16x16x32_bf16(ak[mt][1], bq[rt][1], z, 0, 0, 0);
                z = __builtin_amdgcn_mfma_f32_16x16x32_bf16(ak[mt][0], bq[rt][0], z, 0, 0, 0);
                st[rt][mt] = z;
            }

        // V^T frags issued early (in flight during softmax): row d = 16*mt + c
        bf16x8 av[4][2];
#pragma unroll
        for (int mt = 0; mt < 4; ++mt)
#pragma unroll
            for (int ks = 0; ks < 2; ++ks)
                av[mt][ks] = *(const bf16x8*)&Vh[(16 * mt + c) * 2048 + k0 + 32 * ks + 8 * g];

        // mask bias per in-lane key (shared by both rt)
        float bv[4][4];
#pragma unroll
        for (int mt = 0; mt < 4; ++mt)
#pragma unroll
            for (int reg = 0; reg < 4; ++reg)
                bv[mt][reg] = bias_sm[k0 + 16 * mt + 4 * g + reg];

#pragma unroll
        for (int rt = 0; rt < 2; ++rt) {
            const int qg = qb + 16 * rt + c;
            float p[4][4];
            float pmax = -INFINITY;
#pragma unroll
            for (int mt = 0; mt < 4; ++mt)
#pragma unroll
                for (int reg = 0; reg < 4; ++reg) {
                    const int kg = k0 + 16 * mt + 4 * g + reg;
                    const float s = st[rt][mt][reg] + ((kg <= qg) ? 0.f : bv[mt][reg]);
                    p[mt][reg] = s;
                    pmax = fmaxf(pmax, s);
                }
            pmax = fmaxf(pmax, __shfl_xor(pmax, 16));
            pmax = fmaxf(pmax, __shfl_xor(pmax, 32));
            if (!__all(pmax <= m_[rt])) {          // defer-rescale (T13, THR=0)
                const float mn = fmaxf(m_[rt], pmax);
                const float alpha = __expf(m_[rt] - mn);   // exp(-inf)=0 on first tile
                m_[rt] = mn; l_[rt] *= alpha;
#pragma unroll
                for (int mt = 0; mt < 4; ++mt) o[rt][mt] *= alpha;
            }
            float ts = 0.f;
#pragma unroll
            for (int mt = 0; mt < 4; ++mt)
#pragma unroll
                for (int reg = 0; reg < 4; ++reg) {
                    const float e = __expf(p[mt][reg] - m_[rt]);
                    p[mt][reg] = e; ts += e;
                }
            ts += __shfl_xor(ts, 16);
            ts += __shfl_xor(ts, 32);
            l_[rt] += ts;

            // pack P -> bf16, write per-wave LDS tile [q=c][key], XOR-swizzled 16B slots
            char* Pr = Pw + rt * 2048 + c * 128;
#pragma unroll
            for (int mt = 0; mt < 4; ++mt) {
                const unsigned w0 = pack_bf162(p[mt][0], p[mt][1]);
                const unsigned w1 = pack_bf162(p[mt][2], p[mt][3]);
                const unsigned long long vw =
                    (unsigned long long)w0 | ((unsigned long long)w1 << 32);
                *(unsigned long long*)(Pr + ((32 * mt + 8 * g) ^ swz)) = vw;
            }
        }

        // O^T += V^T * P : B-frag = P[key][q] from swizzled LDS (keys 8*g..8*g+7)
#pragma unroll
        for (int rt = 0; rt < 2; ++rt) {
            const char* Pr = Pw + rt * 2048 + c * 128;
            const bf16x8 pb0 = *(const bf16x8*)(Pr + ((0  + 16 * g) ^ swz));
            const bf16x8 pb1 = *(const bf16x8*)(Pr + ((64 + 16 * g) ^ swz));
#pragma unroll
            for (int mt = 0; mt < 4; ++mt) {
                o[rt][mt] = __builtin_amdgcn_mfma_f32_16x16x32_bf16(av[mt][0], pb0, o[rt][mt], 0, 0, 0);
                o[rt][mt] = __builtin_amdgcn_mfma_f32_16x16x32_bf16(av[mt][1], pb1, o[rt][mt], 0, 0, 0);
            }
        }
    }

    // epilogue: O^T frag -> AO[tok][h*64+d] fp32
#pragma unroll
    for (int rt = 0; rt < 2; ++rt) {
        const float inv = 1.f / l_[rt];
        const size_t tok = (size_t)(b * 2048 + qb + 16 * rt + c);
#pragma unroll
        for (int mt = 0; mt < 4; ++mt)
#pragma unroll
            for (int reg = 0; reg < 4; ++reg)
                AO[tok * 1024 + h * 64 + 16 * mt + 4 * g + reg] = o[rt][mt][reg] * inv;
    }
}

// ---------------- output projection: AO(4096x1024) @ Wo(1024x1024) + bo -------
__launch_bounds__(256)
__global__ void out_proj_kernel(const float* __restrict__ ao,
                                const float* __restrict__ Wo,
                                const float* __restrict__ bo,
                                float* __restrict__ out) {
    __shared__ float Asm[16][132];
    __shared__ float Bsm[16][64];
    const int tid = threadIdx.x;
    const int tx = tid & 15, ty = tid >> 4;
    const int m0 = blockIdx.y * 128;
    const int n0 = blockIdx.x * 64;
    float acc[8][4];
#pragma unroll
    for (int r = 0; r < 8; ++r)
#pragma unroll
        for (int c = 0; c < 4; ++c) acc[r][c] = 0.f;

    for (int k0 = 0; k0 < 1024; k0 += 16) {
#pragma unroll
        for (int j = 0; j < 2; ++j) {
            const int f = tid + 256 * j;
            const int m = f >> 2, k4 = (f & 3) << 2;
            const float4 av = *(const float4*)&ao[(m0 + m) * 1024 + k0 + k4];
            Asm[k4 + 0][m] = av.x; Asm[k4 + 1][m] = av.y;
            Asm[k4 + 2][m] = av.z; Asm[k4 + 3][m] = av.w;
        }
        {
            const int kb = tid >> 4, n4 = (tid & 15) << 2;
            *(float4*)&Bsm[kb][n4] = *(const float4*)&Wo[(k0 + kb) * 1024 + n0 + n4];
        }
        __syncthreads();
#pragma unroll
        for (int kk = 0; kk < 16; ++kk) {
            const float4 a0 = *(const float4*)&Asm[kk][8 * ty];
            const float4 a1 = *(const float4*)&Asm[kk][8 * ty + 4];
            const float4 b0 = *(const float4*)&Bsm[kk][4 * tx];
            const float a[8] = {a0.x,a0.y,a0.z,a0.w,a1.x,a1.y,a1.z,a1.w};
            const float bb[4] = {b0.x,b0.y,b0.z,b0.w};
#pragma unroll
            for (int r = 0; r < 8; ++r)
#pragma unroll
                for (int c = 0; c < 4; ++c) acc[r][c] += a[r] * bb[c];
        }
        __syncthreads();
    }
#pragma unroll
    for (int r = 0; r < 8; ++r) {
        const int row = m0 + 8 * ty + r;
        const float4 bv = *(const float4*)&bo[n0 + 4 * tx];
        const float4 st = make_float4(acc[r][0] + bv.x, acc[r][1] + bv.y,
                                      acc[r][2] + bv.z, acc[r][3] + bv.w);
        *(float4*)&out[row * 1024 + n0 + 4 * tx] = st;
    }
}

extern "C" void kernel_launch(void* const* d_in, const int* in_sizes, int n_in,
                              void* d_out, int out_size, void* d_ws, size_t ws_size,
                              hipStream_t stream) {
    const float* x  = (const float*)d_in[0];
    const float* Wq = (const float*)d_in[1];
    const float* bq = (const float*)d_in[2];
    const float* Wk = (const float*)d_in[3];
    const float* bk = (const float*)d_in[4];
    const float* Wv = (const float*)d_in[5];
    const float* bv = (const float*)d_in[6];
    const float* Wo = (const float*)d_in[7];
    const float* bo = (const float*)d_in[8];
    const float* fc = (const float*)d_in[9];
    const float* fs = (const float*)d_in[10];
    const void*  am = d_in[11];

    char* ws = (char*)d_ws;
    __hip_bfloat16* QB = (__hip_bfloat16*)(ws + OFF_QB);
    __hip_bfloat16* KB = (__hip_bfloat16*)(ws + OFF_KB);
    __hip_bfloat16* VT = (__hip_bfloat16*)(ws + OFF_VT);
    float* AO    = (float*)(ws + OFF_AO);
    float* mbias = (float*)(ws + OFF_MB);
    float* out   = (float*)d_out;

    hipLaunchKernelGGL(mask_canon_kernel, dim3(1), dim3(1024), 0, stream, am, mbias);
    hipLaunchKernelGGL(qkv_rope_kernel, dim3(16, 32), dim3(256), 0, stream,
                       x, Wq, bq, Wk, bk, Wv, bv, fc, fs, QB, KB, VT);
    hipLaunchKernelGGL(attn_kernel, dim3(16, 16, 2), dim3(256), 0, stream,
                       QB, KB, VT, mbias, AO);
    hipLaunchKernelGGL(out_proj_kernel, dim3(16, 32), dim3(256), 0, stream,
                       AO, Wo, bo, out);
}

// Round 3
// 188.289 us; speedup vs baseline: 5.5220x; 2.4986x over previous
//
#include <hip/hip_runtime.h>
#include <hip/hip_bf16.h>
#include <math.h>

// Problem constants: B=2, S=2048, D=1024, HQ=16, HKV=8, DK=DV=64
typedef __attribute__((ext_vector_type(8))) short bf16x8;   // 8 bf16 (4 VGPRs)
typedef __attribute__((ext_vector_type(4))) float f32x4;

// ws layout (byte offsets)
#define OFF_XB  0ull             // bf16 [4096][1024]   8 MB
#define OFF_WT  (8ull<<20)       // bf16 [2048][1024]   4 MB  ([Wq|Wk|Wv]^T)
#define OFF_WO  (12ull<<20)      // bf16 [1024][1024]   2 MB  (Wo^T)
#define OFF_QB  (14ull<<20)      // bf16 [2][16][2048][64]  8 MB (RoPE'd, pre-scaled 1/8)
#define OFF_KB  (22ull<<20)      // bf16 [2][8][2048][64]   4 MB (RoPE'd)
#define OFF_VT  (26ull<<20)      // bf16 [2][8][64][2048]   4 MB (V^T)
#define OFF_AO  (30ull<<20)      // bf16 [4096][1024]   8 MB (attn out)
#define OFF_MB  (38ull<<20)      // f32  [2][2048] mask bias (0 / -1e30)

__device__ inline unsigned pack_bf162(float a, float b) {
    __hip_bfloat162 t = __float22bfloat162_rn(make_float2(a, b));  // a -> low 16 bits
    return *(unsigned*)&t;
}

__device__ inline void gload16(const void* g, void* l) {
    __builtin_amdgcn_global_load_lds(
        (const __attribute__((address_space(1))) void*)g,
        (__attribute__((address_space(3))) void*)l, 16, 0, 0);
}

// ---------------- prep: x->bf16, W transposes->bf16, mask canon ----------------
// blocks 0..1023: XB   | 1024..3071: WT | 3072..4095: WoT | 4096: mask
__launch_bounds__(256)
__global__ void prep_kernel(const float* __restrict__ x,
                            const float* __restrict__ Wq, const float* __restrict__ Wk,
                            const float* __restrict__ Wv, const float* __restrict__ Wo,
                            const void* __restrict__ mraw,
                            __hip_bfloat16* __restrict__ XB,
                            __hip_bfloat16* __restrict__ WT,
                            __hip_bfloat16* __restrict__ WoT,
                            float* __restrict__ mbias) {
    __shared__ float T[32][33];
    __shared__ int bad01, badf;
    const int tid = threadIdx.x;
    const int bid = blockIdx.x;
    if (bid < 1024) {                       // x -> bf16
        const int base = bid * 4096;
#pragma unroll
        for (int i = 0; i < 4; ++i) {
            const int e = base + (i * 256 + tid) * 4;
            const float4 v = *(const float4*)&x[e];
            uint2 pk;
            pk.x = pack_bf162(v.x, v.y);
            pk.y = pack_bf162(v.z, v.w);
            *(uint2*)&XB[e] = pk;
        }
    } else if (bid < 4096) {                // W transposes
        const float* src; int ldn, nbase; __hip_bfloat16* dst; int n0, k0;
        if (bid < 3072) {
            const int tb = bid - 1024;
            const int kt = tb >> 6, nt = tb & 63;
            n0 = nt * 32; k0 = kt * 32; dst = WT;
            if (n0 < 1024)      { src = Wq; ldn = 1024; nbase = n0; }
            else if (n0 < 1536) { src = Wk; ldn = 512;  nbase = n0 - 1024; }
            else                { src = Wv; ldn = 512;  nbase = n0 - 1536; }
        } else {
            const int tb = bid - 3072;
            const int kt = tb >> 5, nt = tb & 31;
            n0 = nt * 32; k0 = kt * 32; dst = WoT;
            src = Wo; ldn = 1024; nbase = n0;
        }
        const int c = tid & 31, r0 = tid >> 5;
#pragma unroll
        for (int i = 0; i < 4; ++i)
            T[r0 + 8 * i][c] = src[(size_t)(k0 + r0 + 8 * i) * ldn + nbase + c];
        __syncthreads();
#pragma unroll
        for (int i = 0; i < 4; ++i) {
            const int nn = r0 + 8 * i;
            dst[(size_t)(n0 + nn) * 1024 + k0 + c] = __float2bfloat16(T[c][nn]);
        }
    } else {                                // mask canonicalization
        if (tid == 0) { bad01 = 0; badf = 0; }
        __syncthreads();
        const unsigned* w = (const unsigned*)mraw;
#pragma unroll
        for (int i = 0; i < 4; ++i) {
            const unsigned v = w[tid * 4 + i];   // first 4 KiB valid for all formats
            if (v > 1u) atomicAdd(&bad01, 1);
            if (v != 0u && v != 0x3F800000u) atomicAdd(&badf, 1);
        }
        __syncthreads();
        const int fmt = (bad01 == 0) ? 0 : ((badf == 0) ? 1 : 2); // 0=i32,1=f32,2=u8
        for (int i = tid; i < 4096; i += 256) {
            bool on;
            if (fmt == 2) on = (((const unsigned char*)mraw)[i] != 0);
            else          on = (w[i] != 0u);
            mbias[i] = on ? 0.f : -1e30f;
        }
    }
}

// ---------------- bf16 MFMA GEMM: D[n][m] = W^T-rows x X-rows, fused epilogues --
// 128x128 tile, BK=64, 4 waves (2n x 2m), per-wave 4x4 16x16 frags.
// LDS XOR-swizzle: slot ^= row&7 (pre-swizzled global src; linear gload_lds dest).
__launch_bounds__(256)
__global__ void qkv_mfma_kernel(const __hip_bfloat16* __restrict__ XB,
                                const __hip_bfloat16* __restrict__ WT,
                                const float* __restrict__ bq, const float* __restrict__ bk,
                                const float* __restrict__ bv,
                                const float* __restrict__ fc, const float* __restrict__ fs,
                                __hip_bfloat16* __restrict__ QB,
                                __hip_bfloat16* __restrict__ KB,
                                __hip_bfloat16* __restrict__ VT) {
    __shared__ __attribute__((aligned(16))) char Asm[16384];  // WT rows [128][64k]
    __shared__ __attribute__((aligned(16))) char Bsm[16384];  // XB rows
    const int tid = threadIdx.x;
    const int lane = tid & 63, wid = tid >> 6;
    const int c = lane & 15, g = lane >> 4;
    const int n0 = blockIdx.x * 128, m0 = blockIdx.y * 128;
    const int wn = (wid >> 1) * 64, wm = (wid & 1) * 64;

    f32x4 acc[4][4];
#pragma unroll
    for (int ni = 0; ni < 4; ++ni)
#pragma unroll
        for (int mj = 0; mj < 4; ++mj) acc[ni][mj] = f32x4{0.f, 0.f, 0.f, 0.f};

    for (int kt = 0; kt < 16; ++kt) {
        const int k0 = kt * 64;
#pragma unroll
        for (int rnd = 0; rnd < 4; ++rnd) {
            const int off = rnd * 4096 + wid * 1024 + lane * 16;
            const int row = off >> 7;
            const int chunk = ((off >> 4) & 7) ^ (row & 7);
            gload16((const char*)WT + ((size_t)(n0 + row) * 1024 + k0 + chunk * 8) * 2,
                    Asm + rnd * 4096 + wid * 1024);
            gload16((const char*)XB + ((size_t)(m0 + row) * 1024 + k0 + chunk * 8) * 2,
                    Bsm + rnd * 4096 + wid * 1024);
        }
        __syncthreads();
#pragma unroll
        for (int ks = 0; ks < 2; ++ks) {
            bf16x8 af[4], bfr[4];
#pragma unroll
            for (int t = 0; t < 4; ++t) {
                const int sl = ((g + 4 * ks) ^ (c & 7)) << 4;
                af[t]  = *(const bf16x8*)(Asm + (wn + 16 * t + c) * 128 + sl);
                bfr[t] = *(const bf16x8*)(Bsm + (wm + 16 * t + c) * 128 + sl);
            }
#pragma unroll
            for (int ni = 0; ni < 4; ++ni)
#pragma unroll
                for (int mj = 0; mj < 4; ++mj)
                    acc[ni][mj] = __builtin_amdgcn_mfma_f32_16x16x32_bf16(
                        af[ni], bfr[mj], acc[ni][mj], 0, 0, 0);
        }
        __syncthreads();
    }

    // epilogue: bias + RoPE + bf16 scatter. lane: features nb..nb+3, token tok.
#pragma unroll
    for (int ni = 0; ni < 4; ++ni) {
        const int nb = n0 + wn + 16 * ni + 4 * g;
        const float* bias; int nloc;
        if (nb < 1024)      { bias = bq; nloc = nb; }
        else if (nb < 1536) { bias = bk; nloc = nb - 1024; }
        else                { bias = bv; nloc = nb - 1536; }
        const float4 b4 = *(const float4*)&bias[nloc];
        const int h = nloc >> 6, dk = nb & 63;
#pragma unroll
        for (int mj = 0; mj < 4; ++mj) {
            const int tok = m0 + wm + 16 * mj + c;
            const int bb = tok >> 11, sp = tok & 2047;
            float v0 = acc[ni][mj][0] + b4.x;
            float v1 = acc[ni][mj][1] + b4.y;
            float v2 = acc[ni][mj][2] + b4.z;
            float v3 = acc[ni][mj][3] + b4.w;
            if (nb < 1536) {
                const int p = sp * 32 + (dk >> 1);
                const float c0 = fc[p], s0 = fs[p];
                const float c1 = fc[p + 1], s1 = fs[p + 1];
                float o0 = v0 * c0 - v1 * s0, o1 = v0 * s0 + v1 * c0;
                float o2 = v2 * c1 - v3 * s1, o3 = v2 * s1 + v3 * c1;
                uint2 pk;
                if (nb < 1024) {
                    o0 *= 0.125f; o1 *= 0.125f; o2 *= 0.125f; o3 *= 0.125f;
                    pk.x = pack_bf162(o0, o1); pk.y = pack_bf162(o2, o3);
                    *(uint2*)&QB[(size_t)((bb * 16 + h) * 2048 + sp) * 64 + dk] = pk;
                } else {
                    pk.x = pack_bf162(o0, o1); pk.y = pack_bf162(o2, o3);
                    *(uint2*)&KB[(size_t)((bb * 8 + h) * 2048 + sp) * 64 + dk] = pk;
                }
            } else {
                const size_t vb = (size_t)((bb * 8 + h) * 64 + dk) * 2048 + sp;
                VT[vb]          = __float2bfloat16(v0);
                VT[vb + 2048]   = __float2bfloat16(v1);
                VT[vb + 4096]   = __float2bfloat16(v2);
                VT[vb + 6144]   = __float2bfloat16(v3);
            }
        }
    }
}

// ---------------- out projection MFMA: out = AO @ Wo + bo ---------------------
__launch_bounds__(256)
__global__ void out_mfma_kernel(const __hip_bfloat16* __restrict__ AOB,
                                const __hip_bfloat16* __restrict__ WoT,
                                const float* __restrict__ bo,
                                float* __restrict__ out) {
    __shared__ __attribute__((aligned(16))) char Asm[16384];
    __shared__ __attribute__((aligned(16))) char Bsm[16384];
    const int tid = threadIdx.x;
    const int lane = tid & 63, wid = tid >> 6;
    const int c = lane & 15, g = lane >> 4;
    const int n0 = blockIdx.x * 128, m0 = blockIdx.y * 128;
    const int wn = (wid >> 1) * 64, wm = (wid & 1) * 64;

    f32x4 acc[4][4];
#pragma unroll
    for (int ni = 0; ni < 4; ++ni)
#pragma unroll
        for (int mj = 0; mj < 4; ++mj) acc[ni][mj] = f32x4{0.f, 0.f, 0.f, 0.f};

    for (int kt = 0; kt < 16; ++kt) {
        const int k0 = kt * 64;
#pragma unroll
        for (int rnd = 0; rnd < 4; ++rnd) {
            const int off = rnd * 4096 + wid * 1024 + lane * 16;
            const int row = off >> 7;
            const int chunk = ((off >> 4) & 7) ^ (row & 7);
            gload16((const char*)WoT + ((size_t)(n0 + row) * 1024 + k0 + chunk * 8) * 2,
                    Asm + rnd * 4096 + wid * 1024);
            gload16((const char*)AOB + ((size_t)(m0 + row) * 1024 + k0 + chunk * 8) * 2,
                    Bsm + rnd * 4096 + wid * 1024);
        }
        __syncthreads();
#pragma unroll
        for (int ks = 0; ks < 2; ++ks) {
            bf16x8 af[4], bfr[4];
#pragma unroll
            for (int t = 0; t < 4; ++t) {
                const int sl = ((g + 4 * ks) ^ (c & 7)) << 4;
                af[t]  = *(const bf16x8*)(Asm + (wn + 16 * t + c) * 128 + sl);
                bfr[t] = *(const bf16x8*)(Bsm + (wm + 16 * t + c) * 128 + sl);
            }
#pragma unroll
            for (int ni = 0; ni < 4; ++ni)
#pragma unroll
                for (int mj = 0; mj < 4; ++mj)
                    acc[ni][mj] = __builtin_amdgcn_mfma_f32_16x16x32_bf16(
                        af[ni], bfr[mj], acc[ni][mj], 0, 0, 0);
        }
        __syncthreads();
    }
#pragma unroll
    for (int ni = 0; ni < 4; ++ni) {
        const int nb = n0 + wn + 16 * ni + 4 * g;
        const float4 b4 = *(const float4*)&bo[nb];
#pragma unroll
        for (int mj = 0; mj < 4; ++mj) {
            const int tok = m0 + wm + 16 * mj + c;
            const f32x4 a = acc[ni][mj];
            const float4 st = make_float4(a[0] + b4.x, a[1] + b4.y,
                                          a[2] + b4.z, a[3] + b4.w);
            *(float4*)&out[(size_t)tok * 1024 + nb] = st;
        }
    }
}

// ---------------- flash attention, bf16 MFMA, swapped operands ----------------
__launch_bounds__(256)
__global__ void attn_kernel(const __hip_bfloat16* __restrict__ QB,
                            const __hip_bfloat16* __restrict__ KB,
                            const __hip_bfloat16* __restrict__ VT,
                            const float* __restrict__ maskb,
                            __hip_bfloat16* __restrict__ AOB) {
    __shared__ float bias_sm[2048];
    __shared__ char  P_lds[4][4096];   // per wave: 2 rt x [16 q][64 key] bf16

    const int tid  = threadIdx.x;
    const int lane = tid & 63, wid = tid >> 6;
    const int c = lane & 15, g = lane >> 4;
    const int h = blockIdx.y, b = blockIdx.z;
    const int qb = blockIdx.x * 128 + wid * 32;

    {
        const float* mb = maskb + b * 2048;
        for (int i = tid; i < 512; i += 256)
            *(float4*)&bias_sm[4 * i] = *(const float4*)&mb[4 * i];
    }

    const __hip_bfloat16* Qh = QB + (size_t)(b * 16 + h)        * 2048 * 64;
    const __hip_bfloat16* Kh = KB + (size_t)(b * 8 + (h >> 1))  * 2048 * 64;
    const __hip_bfloat16* Vh = VT + (size_t)(b * 8 + (h >> 1))  * 64 * 2048;

    bf16x8 bq[2][2];
#pragma unroll
    for (int rt = 0; rt < 2; ++rt)
#pragma unroll
        for (int ks = 0; ks < 2; ++ks)
            bq[rt][ks] = *(const bf16x8*)&Qh[(qb + 16 * rt + c) * 64 + 32 * ks + 8 * g];

    __syncthreads();

    f32x4 o[2][4];
#pragma unroll
    for (int rt = 0; rt < 2; ++rt)
#pragma unroll
        for (int mt = 0; mt < 4; ++mt) o[rt][mt] = f32x4{0.f, 0.f, 0.f, 0.f};
    float m_[2] = {-INFINITY, -INFINITY}, l_[2] = {0.f, 0.f};

    char* Pw = &P_lds[wid][0];
    const int swz = (c & 7) << 4;

    for (int kt = 0; kt < 32; ++kt) {
        const int k0 = kt * 64;
        bf16x8 ak[4][2];
#pragma unroll
        for (int mt = 0; mt < 4; ++mt)
#pragma unroll
            for (int ks = 0; ks < 2; ++ks)
                ak[mt][ks] = *(const bf16x8*)&Kh[(k0 + 16 * mt + c) * 64 + 32 * ks + 8 * g];

        f32x4 st[2][4];
#pragma unroll
        for (int rt = 0; rt < 2; ++rt)
#pragma unroll
            for (int mt = 0; mt < 4; ++mt) {
                f32x4 z = f32x4{0.f, 0.f, 0.f, 0.f};
                z = __builtin_amdgcn_mfma_f32_16x16x32_bf16(ak[mt][1], bq[rt][1], z, 0, 0, 0);
                z = __builtin_amdgcn_mfma_f32_16x16x32_bf16(ak[mt][0], bq[rt][0], z, 0, 0, 0);
                st[rt][mt] = z;
            }

        bf16x8 av[4][2];
#pragma unroll
        for (int mt = 0; mt < 4; ++mt)
#pragma unroll
            for (int ks = 0; ks < 2; ++ks)
                av[mt][ks] = *(const bf16x8*)&Vh[(16 * mt + c) * 2048 + k0 + 32 * ks + 8 * g];

        float bv[4][4];
#pragma unroll
        for (int mt = 0; mt < 4; ++mt)
#pragma unroll
            for (int reg = 0; reg < 4; ++reg)
                bv[mt][reg] = bias_sm[k0 + 16 * mt + 4 * g + reg];

#pragma unroll
        for (int rt = 0; rt < 2; ++rt) {
            const int qg = qb + 16 * rt + c;
            float p[4][4];
            float pmax = -INFINITY;
#pragma unroll
            for (int mt = 0; mt < 4; ++mt)
#pragma unroll
                for (int reg = 0; reg < 4; ++reg) {
                    const int kg = k0 + 16 * mt + 4 * g + reg;
                    const float s = st[rt][mt][reg] + ((kg <= qg) ? 0.f : bv[mt][reg]);
                    p[mt][reg] = s;
                    pmax = fmaxf(pmax, s);
                }
            pmax = fmaxf(pmax, __shfl_xor(pmax, 16));
            pmax = fmaxf(pmax, __shfl_xor(pmax, 32));
            if (!__all(pmax <= m_[rt])) {
                const float mn = fmaxf(m_[rt], pmax);
                const float alpha = __expf(m_[rt] - mn);
                m_[rt] = mn; l_[rt] *= alpha;
#pragma unroll
                for (int mt = 0; mt < 4; ++mt) o[rt][mt] *= alpha;
            }
            float ts = 0.f;
#pragma unroll
            for (int mt = 0; mt < 4; ++mt)
#pragma unroll
                for (int reg = 0; reg < 4; ++reg) {
                    const float e = __expf(p[mt][reg] - m_[rt]);
                    p[mt][reg] = e; ts += e;
                }
            ts += __shfl_xor(ts, 16);
            ts += __shfl_xor(ts, 32);
            l_[rt] += ts;

            char* Pr = Pw + rt * 2048 + c * 128;
#pragma unroll
            for (int mt = 0; mt < 4; ++mt) {
                const unsigned w0 = pack_bf162(p[mt][0], p[mt][1]);
                const unsigned w1 = pack_bf162(p[mt][2], p[mt][3]);
                const unsigned long long vw =
                    (unsigned long long)w0 | ((unsigned long long)w1 << 32);
                *(unsigned long long*)(Pr + ((32 * mt + 8 * g) ^ swz)) = vw;
            }
        }

#pragma unroll
        for (int rt = 0; rt < 2; ++rt) {
            const char* Pr = Pw + rt * 2048 + c * 128;
            const bf16x8 pb0 = *(const bf16x8*)(Pr + ((0  + 16 * g) ^ swz));
            const bf16x8 pb1 = *(const bf16x8*)(Pr + ((64 + 16 * g) ^ swz));
#pragma unroll
            for (int mt = 0; mt < 4; ++mt) {
                o[rt][mt] = __builtin_amdgcn_mfma_f32_16x16x32_bf16(av[mt][0], pb0, o[rt][mt], 0, 0, 0);
                o[rt][mt] = __builtin_amdgcn_mfma_f32_16x16x32_bf16(av[mt][1], pb1, o[rt][mt], 0, 0, 0);
            }
        }
    }

#pragma unroll
    for (int rt = 0; rt < 2; ++rt) {
        const float inv = 1.f / l_[rt];
        const size_t tok = (size_t)(b * 2048 + qb + 16 * rt + c);
#pragma unroll
        for (int mt = 0; mt < 4; ++mt) {
            uint2 pk;
            pk.x = pack_bf162(o[rt][mt][0] * inv, o[rt][mt][1] * inv);
            pk.y = pack_bf162(o[rt][mt][2] * inv, o[rt][mt][3] * inv);
            *(uint2*)&AOB[tok * 1024 + h * 64 + 16 * mt + 4 * g] = pk;
        }
    }
}

extern "C" void kernel_launch(void* const* d_in, const int* in_sizes, int n_in,
                              void* d_out, int out_size, void* d_ws, size_t ws_size,
                              hipStream_t stream) {
    const float* x  = (const float*)d_in[0];
    const float* Wq = (const float*)d_in[1];
    const float* bq = (const float*)d_in[2];
    const float* Wk = (const float*)d_in[3];
    const float* bk = (const float*)d_in[4];
    const float* Wv = (const float*)d_in[5];
    const float* bv = (const float*)d_in[6];
    const float* Wo = (const float*)d_in[7];
    const float* bo = (const float*)d_in[8];
    const float* fc = (const float*)d_in[9];
    const float* fs = (const float*)d_in[10];
    const void*  am = d_in[11];

    char* ws = (char*)d_ws;
    __hip_bfloat16* XB  = (__hip_bfloat16*)(ws + OFF_XB);
    __hip_bfloat16* WT  = (__hip_bfloat16*)(ws + OFF_WT);
    __hip_bfloat16* WoT = (__hip_bfloat16*)(ws + OFF_WO);
    __hip_bfloat16* QB  = (__hip_bfloat16*)(ws + OFF_QB);
    __hip_bfloat16* KB  = (__hip_bfloat16*)(ws + OFF_KB);
    __hip_bfloat16* VT  = (__hip_bfloat16*)(ws + OFF_VT);
    __hip_bfloat16* AOB = (__hip_bfloat16*)(ws + OFF_AO);
    float* mbias = (float*)(ws + OFF_MB);
    float* out   = (float*)d_out;

    hipLaunchKernelGGL(prep_kernel, dim3(4097), dim3(256), 0, stream,
                       x, Wq, Wk, Wv, Wo, am, XB, WT, WoT, mbias);
    hipLaunchKernelGGL(qkv_mfma_kernel, dim3(16, 32), dim3(256), 0, stream,
                       XB, WT, bq, bk, bv, fc, fs, QB, KB, VT);
    hipLaunchKernelGGL(attn_kernel, dim3(16, 16, 2), dim3(256), 0, stream,
                       QB, KB, VT, mbias, AOB);
    hipLaunchKernelGGL(out_mfma_kernel, dim3(8, 32), dim3(256), 0, stream,
                       AOB, WoT, bo, out);
}